// Round 18
// baseline (501.856 us; speedup 1.0000x reference)
//
#include <hip/hip_runtime.h>

typedef float  f4     __attribute__((ext_vector_type(4)));
typedef float  f2     __attribute__((ext_vector_type(2)));
typedef short  short8 __attribute__((ext_vector_type(8)));

#define B_ 32
#define D_ 128
#define T_ 1024
#define K_ 4096
#define NROWS (B_ * T_)   // 32768
#define LPX 132
#define INF_ 3.4e38f

#define SCHED_FENCE() __builtin_amdgcn_sched_barrier(0)

// numpy computes t = a*a elementwise, THEN pairwise-sums (no fma fusion).
__device__ __forceinline__ float opaquef(float x) { asm volatile("" : "+v"(x)); return x; }

// numpy pairwise_sum base case for n=128: 8 accumulators,
// ((r0+r1)+(r2+r3))+((r4+r5)+(r6+r7)). Bit-exact replica (r12-proven).
__device__ float np_sumsq128(const float* a) {
  float r[8];
#pragma unroll
  for (int j = 0; j < 8; ++j) r[j] = opaquef(a[j] * a[j]);
#pragma unroll
  for (int i = 8; i < 128; i += 8) {
#pragma unroll
    for (int j = 0; j < 8; ++j) r[j] = r[j] + opaquef(a[i + j] * a[i + j]);
  }
  return ((r[0] + r[1]) + (r[2] + r[3])) + ((r[4] + r[5]) + (r[6] + r[7]));
}

// round-to-nearest-even fp32 -> bf16 (deterministic, rel err <= 2^-9)
__device__ __forceinline__ short bf16_rne(float f) {
  unsigned u = __float_as_uint(f);
  unsigned r = (u + 0x7FFFu + ((u >> 16) & 1u)) >> 16;
  return (short)r;
}

__global__ void wsq_kernel(const float* __restrict__ W, float* __restrict__ wsq,
                           unsigned* __restrict__ maxwsq) {
  int k = blockIdx.x * blockDim.x + threadIdx.x;
  if (k < K_) {
    float s = np_sumsq128(W + (size_t)k * D_);
    wsq[k] = s;
    atomicMax(maxwsq, __float_as_uint(s));  // positive floats: uint order == float order
  }
}

// Wbf fragment layout for mfma_f32_16x16x32_bf16 B-operand:
// elem e = ((ct*4+kk)*64 + lane)*8 + j holds bf16(W[ct*16 + (lane&15)][kk*32 + (lane>>4)*8 + j])
__global__ void wbf_prep_kernel(const float* __restrict__ W, short* __restrict__ Wbf) {
  int e = blockIdx.x * 256 + threadIdx.x;   // 524288 total
  int j = e & 7, lane = (e >> 3) & 63, kk = (e >> 9) & 3, ct = e >> 11;
  int code = (ct << 4) + (lane & 15);
  int k = (kk << 5) + (((lane >> 4) & 3) << 3) + j;
  Wbf[e] = bf16_rne(W[(size_t)code * D_ + k]);
}

// B-fragment load: linear byte pointer + imm offsets (r14-proven)
#define LDB(R0, R1, R2, R3, WQ)               \
  R0 = *(const short8*)(pwb);                 \
  R1 = *(const short8*)(pwb + 1024);          \
  R2 = *(const short8*)(pwb + 2048);          \
  R3 = *(const short8*)(pwb + 3072);          \
  WQ = *pwq;                                  \
  pwb += 4096; pwq += 16;

// top-2+m3 tracker (r15-validated): m1<=m2<=m3; i1,i2 track m1,m2
#define TOP3_UPD(T, J, U, KK)                                                  \
  do {                                                                         \
    bool c1 = (U) < m1[T][J], c2 = (U) < m2[T][J];                             \
    m3[T][J] = __builtin_amdgcn_fmed3f((U), m2[T][J], m3[T][J]);               \
    m2[T][J] = __builtin_amdgcn_fmed3f((U), m1[T][J], m2[T][J]);               \
    m1[T][J] = fminf((U), m1[T][J]);                                           \
    i2[T][J] = c1 ? i1[T][J] : (c2 ? (KK) : i2[T][J]);                         \
    i1[T][J] = c1 ? (KK) : i1[T][J];                                           \
  } while (0)

// Single-sweep consume: 8 MFMAs (same split-chain structure as r12-r16 => WIN
// accumulation-order term unchanged), then per-slot top-3 tracking.
#define CONSUME_MIN(B0, B1, B2, B3, WQ, CT)                                    \
  do {                                                                         \
    f4 z = {0.f, 0.f, 0.f, 0.f};                                               \
    f4 A0 = __builtin_amdgcn_mfma_f32_16x16x32_bf16(afr0[0], B0, z, 0, 0, 0);  \
    A0 = __builtin_amdgcn_mfma_f32_16x16x32_bf16(afr0[1], B1, A0, 0, 0, 0);    \
    f4 A1 = __builtin_amdgcn_mfma_f32_16x16x32_bf16(afr0[2], B2, z, 0, 0, 0);  \
    A1 = __builtin_amdgcn_mfma_f32_16x16x32_bf16(afr0[3], B3, A1, 0, 0, 0);    \
    f4 C0 = __builtin_amdgcn_mfma_f32_16x16x32_bf16(afr1[0], B0, z, 0, 0, 0);  \
    C0 = __builtin_amdgcn_mfma_f32_16x16x32_bf16(afr1[1], B1, C0, 0, 0, 0);    \
    f4 C1 = __builtin_amdgcn_mfma_f32_16x16x32_bf16(afr1[2], B2, z, 0, 0, 0);  \
    C1 = __builtin_amdgcn_mfma_f32_16x16x32_bf16(afr1[3], B3, C1, 0, 0, 0);    \
    const int kk_ = ((CT) << 4) + cidx;                                        \
    _Pragma("unroll")                                                          \
    for (int j = 0; j < 4; ++j) {                                              \
      float u0 = __fmaf_rn(-2.f, A0[j] + A1[j], WQ);                           \
      TOP3_UPD(0, j, u0, kk_);                                                 \
      float u1 = __fmaf_rn(-2.f, C0[j] + C1[j], WQ);                           \
      TOP3_UPD(1, j, u1, kk_);                                                 \
    }                                                                          \
  } while (0)

// Single-sweep MFMA filter (r16 skeleton + r15 tracker). Block = 32 rows,
// 4 waves each sweeping a 64-ct quarter once. Per-lane top-2 inserted when
// within window; m3 within window (or cand overflow) => flag row for the
// exact LDS-staged scan. WIN formula identical to r11-r16 (validated).
__global__ __launch_bounds__(256) void filter_kernel(
    const float* __restrict__ x, const short* __restrict__ Wbf,
    const float* __restrict__ wsq, const unsigned* __restrict__ maxwsq,
    float* __restrict__ xsq_g, int* __restrict__ cnt, int* __restrict__ cand,
    int* __restrict__ flags, int* __restrict__ nflag, int* __restrict__ flist) {
  __shared__ float xs[32][LPX];
  __shared__ float xsqs[32];
  __shared__ float umin_sh[32][4];
  const int tid = threadIdx.x;
  const int blkrow = blockIdx.x * 32;
  const int b = blockIdx.x >> 5, t0 = (blockIdx.x & 31) << 5;

  {  // stage x rows (coalesced along t)
    int tt = tid & 31, d0 = (tid >> 5) * 16;
    for (int dd = 0; dd < 16; ++dd) {
      int d = d0 + dd;
      xs[tt][d] = x[((size_t)b * D_ + d) * T_ + t0 + tt];
    }
  }
  __syncthreads();
  if (tid < 32) {
    float s = np_sumsq128(&xs[tid][0]);
    xsqs[tid] = s;
    xsq_g[blkrow + tid] = s;
  }
  __syncthreads();

  const int w = tid >> 6, lane = tid & 63;
  const int cidx = lane & 15;         // code within ct tile
  const int q = lane >> 4;            // k-slice / C-row group

  // A fragments for both row-tiles: lane holds row t*16+(lane&15), k = kk*32+q*8+j
  short8 afr0[4], afr1[4];
#pragma unroll
  for (int kk = 0; kk < 4; ++kk)
#pragma unroll
    for (int j = 0; j < 8; ++j) {
      int k = (kk << 5) + (q << 3) + j;
      afr0[kk][j] = bf16_rne(xs[cidx][k]);
      afr1[kk][j] = bf16_rne(xs[16 + cidx][k]);
    }

  const float mw = sqrtf(__uint_as_float(*maxwsq)) * 1.0001f;

  float m1[2][4], m2[2][4], m3[2][4];
  int   i1[2][4], i2[2][4];
#pragma unroll
  for (int t = 0; t < 2; ++t)
#pragma unroll
    for (int j = 0; j < 4; ++j) {
      m1[t][j] = INF_; m2[t][j] = INF_; m3[t][j] = INF_;
      i1[t][j] = 0x7fffffff; i2[t][j] = 0x7fffffff;
    }
  const int ct0 = w << 6;             // this wave's 64-ct quarter

  {
    const char*  pwb = (const char*)Wbf + (size_t)ct0 * 4096 + (size_t)lane * 16;
    const float* pwq = wsq + (ct0 << 4) + cidx;
    short8 p0, p1, p2, p3, n0, n1, n2, n3;
    float wqc, wqn;
    LDB(p0, p1, p2, p3, wqc)          // ct0
    for (int s = 0; s < 32; ++s) {
      const int c = ct0 + s * 2;
      LDB(n0, n1, n2, n3, wqn)        // ct0+2s+1
      SCHED_FENCE();
      CONSUME_MIN(p0, p1, p2, p3, wqc, c);
      SCHED_FENCE();
      LDB(p0, p1, p2, p3, wqc)        // ct0+2s+2 (last iter overreads mapped slack)
      SCHED_FENCE();
      CONSUME_MIN(n0, n1, n2, n3, wqn, c + 1);
      SCHED_FENCE();
    }
  }

  // min over the 16 code-lanes (butterfly) -> per-row quarter-min
  float lim[2][4];
#pragma unroll
  for (int t = 0; t < 2; ++t)
#pragma unroll
    for (int j = 0; j < 4; ++j) {
      float m = m1[t][j];
#pragma unroll
      for (int mask = 1; mask < 16; mask <<= 1)
        m = fminf(m, __shfl_xor(m, mask));
      if (cidx == 0) umin_sh[t * 16 + (q << 2) + j][w] = m;
    }
  __syncthreads();
  // merge quarters + window (same WIN formula as r11-r16)
#pragma unroll
  for (int t = 0; t < 2; ++t)
#pragma unroll
    for (int j = 0; j < 4; ++j) {
      int rl = t * 16 + (q << 2) + j;
      float mg = fminf(fminf(umin_sh[rl][0], umin_sh[rl][1]),
                       fminf(umin_sh[rl][2], umin_sh[rl][3]));
      float xn = sqrtf(xsqs[rl]) * 1.0001f;
      lim[t][j] = mg + 4.f * (0.0079f * xn * mw + 1e-5f) + 2.6e-5f;
    }

  // insertion: lane contributes top-2 if within window; m3 within window (or
  // overflow) => possible 3rd-in-lane miss => flag row exactly-once (r16 push).
#pragma unroll
  for (int t = 0; t < 2; ++t)
#pragma unroll
    for (int j = 0; j < 4; ++j) {
      int row = blkrow + t * 16 + (q << 2) + j;
      bool ovf = false;
      if (m1[t][j] <= lim[t][j]) {
        int pos = atomicAdd(&cnt[row], 1);
        if (pos < 16) cand[(row << 4) + pos] = i1[t][j]; else ovf = true;
      }
      if (m2[t][j] <= lim[t][j]) {
        int pos = atomicAdd(&cnt[row], 1);
        if (pos < 16) cand[(row << 4) + pos] = i2[t][j]; else ovf = true;
      }
      if (ovf || m3[t][j] <= lim[t][j]) {
        int old = atomicOr(&flags[row], 1);
        if (old == 0) { int p = atomicAdd(nflag, 1); flist[p & (NROWS - 1)] = row; }
      }
    }
}

// Exact rescore: lane c replays the bit-exact np fp32 pipeline for candidate c;
// lexicographic (v, k) min == np.argmin first-occurrence. Flagged rows are
// handled by exact_kernel. (r16-proven)
__global__ __launch_bounds__(256) void rescore_kernel(
    const float* __restrict__ x, const float* __restrict__ W,
    const float* __restrict__ wsq, const float* __restrict__ xsq,
    const int* __restrict__ cnt, const int* __restrict__ cand,
    const int* __restrict__ flags,
    int* __restrict__ qout, float* __restrict__ out2) {
  const int wid = threadIdx.x >> 6, lane = threadIdx.x & 63;
  const int r = blockIdx.x * 4 + wid;
  if (flags[r]) return;   // exact_kernel owns this row
  int c = cnt[r]; if (c > 16) c = 16;
  int best;
  if (c == 1) {
    best = cand[r << 4] & (K_ - 1);
  } else {
    const float* xr = x + ((size_t)(r >> 10) * D_) * T_ + (r & 1023);
    float v = INF_; int k = 0x7fffffff;
    if (lane < c) {
      k = cand[(r << 4) + lane] & (K_ - 1);
      const float* wr = W + (size_t)k * D_;
      float mm = 0.f;
#pragma unroll 16
      for (int d = 0; d < D_; ++d)
        mm = __fmaf_rn(xr[(size_t)d * T_], wr[d], mm);   // ascending-d sgemm chain
      v = __fadd_rn(__fmaf_rn(-2.f, mm, wsq[k]), xsq[r]);  // RN(wq-2mm) then +xsq
    }
#pragma unroll
    for (int mask = 1; mask < 16; mask <<= 1) {
      float vo = __shfl_xor(v, mask); int ko = __shfl_xor(k, mask);
      if (vo < v || (vo == v && ko < k)) { v = vo; k = ko; }
    }
    best = k & (K_ - 1);
  }
  if (lane == 0) { qout[r] = best; out2[r] = (float)best; }
}

// Exact full-scan for flagged rows (expected ~41). LDS-staged coalesced W;
// bit-exact np chain; lexicographic (v,k) min. (r16-proven)
__global__ __launch_bounds__(256) void exact_kernel(
    const float* __restrict__ x, const float* __restrict__ W,
    const float* __restrict__ wsq, const float* __restrict__ xsq,
    const int* __restrict__ nflag, const int* __restrict__ flist,
    int* __restrict__ qout, float* __restrict__ out2) {
  __shared__ float xrow[128];
  __shared__ float wl[64][130];   // pad 130
  int n = *nflag;
  for (int fi = blockIdx.x; fi < n; fi += gridDim.x) {
    int r = flist[fi] & (NROWS - 1);
    const float* xr = x + ((size_t)(r >> 10) * D_) * T_ + (r & 1023);
    if (threadIdx.x < 128) xrow[threadIdx.x] = xr[(size_t)threadIdx.x * T_];
    float v = INF_; int kb = 0x7fffffff;
    for (int s = 0; s < K_ / 64; ++s) {
      __syncthreads();
      const f2* src = (const f2*)(W + (size_t)s * 64 * D_);
      for (int e = threadIdx.x; e < 4096; e += 256)
        *(f2*)&wl[e >> 6][(e & 63) * 2] = src[e];
      __syncthreads();
      if (threadIdx.x < 64) {
        int k = s * 64 + threadIdx.x;
        float mm = 0.f;
#pragma unroll 16
        for (int d = 0; d < D_; ++d)
          mm = __fmaf_rn(xrow[d], wl[threadIdx.x][d], mm);
        float vv = __fadd_rn(__fmaf_rn(-2.f, mm, wsq[k]), xsq[r]);
        if (vv < v) { v = vv; kb = k; }
      }
    }
    if (threadIdx.x < 64) {
#pragma unroll
      for (int mask = 1; mask < 64; mask <<= 1) {
        float vo = __shfl_xor(v, mask); int ko = __shfl_xor(kb, mask);
        if (vo < v || (vo == v && ko < kb)) { v = vo; kb = ko; }
      }
      if (threadIdx.x == 0) {
        int best = kb & (K_ - 1);
        qout[r] = best; out2[r] = (float)best;
      }
    }
    __syncthreads();
  }
}

// out0[r, d] = W[q[r], d]  — coalesced along d
__global__ void scatter0_kernel(const float* __restrict__ W,
                                const int* __restrict__ q,
                                float* __restrict__ out0) {
  int r = blockIdx.x * 2 + (threadIdx.x >> 7);
  int d = threadIdx.x & 127;
  int k = q[r] & (K_ - 1);
  out0[(size_t)r * D_ + d] = W[(size_t)k * D_ + d];
}

// out1[b, d, t] = W[q[b,t], d]  — coalesced along t
__global__ void scatter1_kernel(const float* __restrict__ W,
                                const int* __restrict__ q,
                                float* __restrict__ out1) {
  int b = blockIdx.x >> 7;
  int d = blockIdx.x & 127;
  for (int t = threadIdx.x; t < T_; t += 256) {
    int k = q[b * T_ + t] & (K_ - 1);
    out1[((size_t)b * D_ + d) * T_ + t] = W[(size_t)k * D_ + d];
  }
}

extern "C" void kernel_launch(void* const* d_in, const int* in_sizes, int n_in,
                              void* d_out, int out_size, void* d_ws, size_t ws_size,
                              hipStream_t stream) {
  const float* x = (const float*)d_in[0];
  const float* W = (const float*)d_in[1];
  float* out  = (float*)d_out;
  float* out0 = out;                           // [B,T,D]  4194304
  float* out1 = out + (size_t)NROWS * D_;      // [B,D,T]  4194304
  float* out2 = out + 2 * (size_t)NROWS * D_;  // [B,T]    32768 (as float)

  // small scratch in ws (532 KB, within the r14/r16-proven envelope)
  float*    wsq   = (float*)d_ws;                               // 16 KB
  float*    xsq   = (float*)((char*)d_ws + (16 << 10));         // 128 KB
  int*      q     = (int*)((char*)d_ws + (144 << 10));          // 128 KB
  int*      cnt   = (int*)((char*)d_ws + (272 << 10));          // 128 KB
  unsigned* maxw  = (unsigned*)((char*)d_ws + (400 << 10));     // 4 B (4K pad)
  int*      flags = (int*)((char*)d_ws + (404 << 10));          // 128 KB

  // big scratch in out0 (read before scatter0 overwrites it; stream-ordered)
  int*   cand  = (int*)out0;                                // 2 MB
  short* Wbf   = (short*)((char*)(void*)out0 + (2 << 20));  // 1 MB
  int*   flist = (int*)((char*)(void*)out0 + (3 << 20));    // 128 KB (also LDB overread slack)
  int*   nflag = (int*)((char*)(void*)out0 + (3 << 20) + (128 << 10));  // 4 B

  // zero cnt + maxw + flags (272K..532K) and nflag
  hipMemsetAsync((char*)d_ws + (272 << 10), 0, (260 << 10) + 64, stream);
  hipMemsetAsync(nflag, 0, 64, stream);
  wsq_kernel<<<K_ / 256, 256, 0, stream>>>(W, wsq, maxw);
  wbf_prep_kernel<<<K_ * D_ / 256, 256, 0, stream>>>(W, Wbf);
  filter_kernel<<<NROWS / 32, 256, 0, stream>>>(x, Wbf, wsq, maxw, xsq, cnt, cand,
                                                flags, nflag, flist);
  rescore_kernel<<<NROWS / 4, 256, 0, stream>>>(x, W, wsq, xsq, cnt, cand, flags, q, out2);
  exact_kernel<<<64, 256, 0, stream>>>(x, W, wsq, xsq, nflag, flist, q, out2);
  scatter0_kernel<<<NROWS / 2, 256, 0, stream>>>(W, q, out0);
  scatter1_kernel<<<B_ * D_, 256, 0, stream>>>(W, q, out1);
}

// Round 19
// 212.667 us; speedup vs baseline: 2.3598x; 2.3598x over previous
//
#include <hip/hip_runtime.h>

typedef float  f4     __attribute__((ext_vector_type(4)));
typedef float  f2     __attribute__((ext_vector_type(2)));
typedef short  short8 __attribute__((ext_vector_type(8)));

#define B_ 32
#define D_ 128
#define T_ 1024
#define K_ 4096
#define NROWS (B_ * T_)   // 32768
#define LPX 132
#define INF_ 3.4e38f

#define SCHED_FENCE() __builtin_amdgcn_sched_barrier(0)
#define MFMA __builtin_amdgcn_mfma_f32_16x16x32_bf16

// numpy computes t = a*a elementwise, THEN pairwise-sums (no fma fusion).
__device__ __forceinline__ float opaquef(float x) { asm volatile("" : "+v"(x)); return x; }

// numpy pairwise_sum base case for n=128: 8 accumulators,
// ((r0+r1)+(r2+r3))+((r4+r5)+(r6+r7)). Bit-exact replica (r12-proven).
__device__ float np_sumsq128(const float* a) {
  float r[8];
#pragma unroll
  for (int j = 0; j < 8; ++j) r[j] = opaquef(a[j] * a[j]);
#pragma unroll
  for (int i = 8; i < 128; i += 8) {
#pragma unroll
    for (int j = 0; j < 8; ++j) r[j] = r[j] + opaquef(a[i + j] * a[i + j]);
  }
  return ((r[0] + r[1]) + (r[2] + r[3])) + ((r[4] + r[5]) + (r[6] + r[7]));
}

// round-to-nearest-even fp32 -> bf16 (deterministic, rel err <= 2^-9)
__device__ __forceinline__ short bf16_rne(float f) {
  unsigned u = __float_as_uint(f);
  unsigned r = (u + 0x7FFFu + ((u >> 16) & 1u)) >> 16;
  return (short)r;
}
__device__ __forceinline__ float bf16_tof(short h) {
  return __uint_as_float(((unsigned)(unsigned short)h) << 16);
}

__global__ void wsq_kernel(const float* __restrict__ W, float* __restrict__ wsq,
                           unsigned* __restrict__ maxwsq) {
  int k = blockIdx.x * blockDim.x + threadIdx.x;
  if (k < K_) {
    float s = np_sumsq128(W + (size_t)k * D_);
    wsq[k] = s;
    atomicMax(maxwsq, __float_as_uint(s));  // positive floats: uint order == float order
  }
}

// Split-bf16 W fragments (hi + residual lo), same layout as before:
// elem e = ((ct*4+kk)*64+lane)*8+j holds W[ct*16+(lane&15)][kk*32+((lane>>4)&3)*8+j]
__global__ void wbf_prep_kernel(const float* __restrict__ W,
                                short* __restrict__ WbfH, short* __restrict__ WbfL) {
  int e = blockIdx.x * 256 + threadIdx.x;   // 524288 total
  int j = e & 7, lane = (e >> 3) & 63, kk = (e >> 9) & 3, ct = e >> 11;
  int code = (ct << 4) + (lane & 15);
  int k = (kk << 5) + (((lane >> 4) & 3) << 3) + j;
  float v = W[(size_t)code * D_ + k];
  short h = bf16_rne(v);
  WbfH[e] = h;
  WbfL[e] = bf16_rne(v - bf16_tof(h));
}

// B-fragment load: hi + lo, linear byte pointers + imm offsets
#define LDB2(H0, H1, H2, H3, L0, L1, L2, L3, WQ)  \
  H0 = *(const short8*)(pwbh);                    \
  H1 = *(const short8*)(pwbh + 1024);             \
  H2 = *(const short8*)(pwbh + 2048);             \
  H3 = *(const short8*)(pwbh + 3072);             \
  L0 = *(const short8*)(pwbl);                    \
  L1 = *(const short8*)(pwbl + 1024);             \
  L2 = *(const short8*)(pwbl + 2048);             \
  L3 = *(const short8*)(pwbl + 3072);             \
  WQ = *pwq;                                      \
  pwbh += 4096; pwbl += 4096; pwq += 16;

// top-2+m3 tracker (r15/r18-validated): m1<=m2<=m3; i1,i2 track m1,m2
#define TOP3_UPD(T, J, U, KK)                                                  \
  do {                                                                         \
    bool c1 = (U) < m1[T][J], c2 = (U) < m2[T][J];                             \
    m3[T][J] = __builtin_amdgcn_fmed3f((U), m2[T][J], m3[T][J]);               \
    m2[T][J] = __builtin_amdgcn_fmed3f((U), m1[T][J], m2[T][J]);               \
    m1[T][J] = fminf((U), m1[T][J]);                                           \
    i2[T][J] = c1 ? i1[T][J] : (c2 ? (KK) : i2[T][J]);                         \
    i1[T][J] = c1 ? (KK) : i1[T][J];                                           \
  } while (0)

// Split-bf16 consume: per row-tile, one chain per kk-half accumulates
// hi*hi + hi*lo + lo*hi (12 MFMA per tile, 24 total). mm error ~1e-6.
#define CONSUME_MIN(H0, H1, H2, H3, L0, L1, L2, L3, WQ, CT)                    \
  do {                                                                         \
    f4 z = {0.f, 0.f, 0.f, 0.f};                                               \
    f4 A0 = MFMA(a0h[0], H0, z, 0, 0, 0);                                      \
    A0 = MFMA(a0h[1], H1, A0, 0, 0, 0);                                        \
    A0 = MFMA(a0h[0], L0, A0, 0, 0, 0);                                        \
    A0 = MFMA(a0h[1], L1, A0, 0, 0, 0);                                        \
    A0 = MFMA(a0l[0], H0, A0, 0, 0, 0);                                        \
    A0 = MFMA(a0l[1], H1, A0, 0, 0, 0);                                        \
    f4 A1 = MFMA(a0h[2], H2, z, 0, 0, 0);                                      \
    A1 = MFMA(a0h[3], H3, A1, 0, 0, 0);                                        \
    A1 = MFMA(a0h[2], L2, A1, 0, 0, 0);                                        \
    A1 = MFMA(a0h[3], L3, A1, 0, 0, 0);                                        \
    A1 = MFMA(a0l[2], H2, A1, 0, 0, 0);                                        \
    A1 = MFMA(a0l[3], H3, A1, 0, 0, 0);                                        \
    f4 C0 = MFMA(a1h[0], H0, z, 0, 0, 0);                                      \
    C0 = MFMA(a1h[1], H1, C0, 0, 0, 0);                                        \
    C0 = MFMA(a1h[0], L0, C0, 0, 0, 0);                                        \
    C0 = MFMA(a1h[1], L1, C0, 0, 0, 0);                                        \
    C0 = MFMA(a1l[0], H0, C0, 0, 0, 0);                                        \
    C0 = MFMA(a1l[1], H1, C0, 0, 0, 0);                                        \
    f4 C1 = MFMA(a1h[2], H2, z, 0, 0, 0);                                      \
    C1 = MFMA(a1h[3], H3, C1, 0, 0, 0);                                        \
    C1 = MFMA(a1h[2], L2, C1, 0, 0, 0);                                        \
    C1 = MFMA(a1h[3], L3, C1, 0, 0, 0);                                        \
    C1 = MFMA(a1l[2], H2, C1, 0, 0, 0);                                        \
    C1 = MFMA(a1l[3], H3, C1, 0, 0, 0);                                        \
    const int kk_ = ((CT) << 4) + cidx;                                        \
    _Pragma("unroll")                                                          \
    for (int j = 0; j < 4; ++j) {                                              \
      float u0 = __fmaf_rn(-2.f, A0[j] + A1[j], WQ);                           \
      TOP3_UPD(0, j, u0, kk_);                                                 \
      float u1 = __fmaf_rn(-2.f, C0[j] + C1[j], WQ);                           \
      TOP3_UPD(1, j, u1, kk_);                                                 \
    }                                                                          \
  } while (0)

// Split-bf16 single-sweep filter (r18 skeleton). mm error ~1e-6 => WIN ~7e-5
// (was 1e-3) => cand>1 only on genuine +xsq-bin ties; flags ~0.
__global__ __launch_bounds__(256) void filter_kernel(
    const float* __restrict__ x, const short* __restrict__ WbfH,
    const short* __restrict__ WbfL,
    const float* __restrict__ wsq, const unsigned* __restrict__ maxwsq,
    float* __restrict__ xsq_g, int* __restrict__ cnt, int* __restrict__ cand,
    int* __restrict__ flags, int* __restrict__ nflag, int* __restrict__ flist) {
  __shared__ float xs[32][LPX];
  __shared__ float xsqs[32];
  __shared__ float umin_sh[32][4];
  const int tid = threadIdx.x;
  const int blkrow = blockIdx.x * 32;
  const int b = blockIdx.x >> 5, t0 = (blockIdx.x & 31) << 5;

  {  // stage x rows (coalesced along t)
    int tt = tid & 31, d0 = (tid >> 5) * 16;
    for (int dd = 0; dd < 16; ++dd) {
      int d = d0 + dd;
      xs[tt][d] = x[((size_t)b * D_ + d) * T_ + t0 + tt];
    }
  }
  __syncthreads();
  if (tid < 32) {
    float s = np_sumsq128(&xs[tid][0]);
    xsqs[tid] = s;
    xsq_g[blkrow + tid] = s;
  }
  __syncthreads();

  const int w = tid >> 6, lane = tid & 63;
  const int cidx = lane & 15;         // code within ct tile
  const int q = lane >> 4;            // k-slice / C-row group

  // A fragments hi+lo for both row-tiles: row t*16+(lane&15), k = kk*32+q*8+j
  short8 a0h[4], a0l[4], a1h[4], a1l[4];
#pragma unroll
  for (int kk = 0; kk < 4; ++kk)
#pragma unroll
    for (int j = 0; j < 8; ++j) {
      int k = (kk << 5) + (q << 3) + j;
      float v0 = xs[cidx][k], v1 = xs[16 + cidx][k];
      short h0 = bf16_rne(v0), h1 = bf16_rne(v1);
      a0h[kk][j] = h0; a0l[kk][j] = bf16_rne(v0 - bf16_tof(h0));
      a1h[kk][j] = h1; a1l[kk][j] = bf16_rne(v1 - bf16_tof(h1));
    }

  const float mw = sqrtf(__uint_as_float(*maxwsq)) * 1.0001f;

  float m1[2][4], m2[2][4], m3[2][4];
  int   i1[2][4], i2[2][4];
#pragma unroll
  for (int t = 0; t < 2; ++t)
#pragma unroll
    for (int j = 0; j < 4; ++j) {
      m1[t][j] = INF_; m2[t][j] = INF_; m3[t][j] = INF_;
      i1[t][j] = 0x7fffffff; i2[t][j] = 0x7fffffff;
    }
  const int ct0 = w << 6;             // this wave's 64-ct quarter

  {
    const char*  pwbh = (const char*)WbfH + (size_t)ct0 * 4096 + (size_t)lane * 16;
    const char*  pwbl = (const char*)WbfL + (size_t)ct0 * 4096 + (size_t)lane * 16;
    const float* pwq  = wsq + (ct0 << 4) + cidx;
    short8 pH0, pH1, pH2, pH3, pL0, pL1, pL2, pL3;
    short8 nH0, nH1, nH2, nH3, nL0, nL1, nL2, nL3;
    float wqc, wqn;
    LDB2(pH0, pH1, pH2, pH3, pL0, pL1, pL2, pL3, wqc)   // ct0
    for (int s = 0; s < 32; ++s) {
      const int c = ct0 + s * 2;
      LDB2(nH0, nH1, nH2, nH3, nL0, nL1, nL2, nL3, wqn)  // ct0+2s+1
      SCHED_FENCE();
      CONSUME_MIN(pH0, pH1, pH2, pH3, pL0, pL1, pL2, pL3, wqc, c);
      SCHED_FENCE();
      LDB2(pH0, pH1, pH2, pH3, pL0, pL1, pL2, pL3, wqc)  // +2 (tail overreads mapped slack)
      SCHED_FENCE();
      CONSUME_MIN(nH0, nH1, nH2, nH3, nL0, nL1, nL2, nL3, wqn, c + 1);
      SCHED_FENCE();
    }
  }

  // min over the 16 code-lanes (butterfly) -> per-row quarter-min
  float lim[2][4];
#pragma unroll
  for (int t = 0; t < 2; ++t)
#pragma unroll
    for (int j = 0; j < 4; ++j) {
      float m = m1[t][j];
#pragma unroll
      for (int mask = 1; mask < 16; mask <<= 1)
        m = fminf(m, __shfl_xor(m, mask));
      if (cidx == 0) umin_sh[t * 16 + (q << 2) + j][w] = m;
    }
  __syncthreads();
  // merge quarters + window. Split-bf16 mm error <= ~1e-6 (rigorous bound
  // 2^-17 xn mw + accum); coefficient 3e-5 gives ~40x margin.
#pragma unroll
  for (int t = 0; t < 2; ++t)
#pragma unroll
    for (int j = 0; j < 4; ++j) {
      int rl = t * 16 + (q << 2) + j;
      float mg = fminf(fminf(umin_sh[rl][0], umin_sh[rl][1]),
                       fminf(umin_sh[rl][2], umin_sh[rl][3]));
      float xn = sqrtf(xsqs[rl]) * 1.0001f;
      lim[t][j] = mg + 4.f * (3e-5f * xn * mw + 1e-5f) + 2.6e-5f;
    }

  // insertion: top-2 if within window; m3 within window (or overflow) => flag
#pragma unroll
  for (int t = 0; t < 2; ++t)
#pragma unroll
    for (int j = 0; j < 4; ++j) {
      int row = blkrow + t * 16 + (q << 2) + j;
      bool ovf = false;
      if (m1[t][j] <= lim[t][j]) {
        int pos = atomicAdd(&cnt[row], 1);
        if (pos < 16) cand[(row << 4) + pos] = i1[t][j]; else ovf = true;
      }
      if (m2[t][j] <= lim[t][j]) {
        int pos = atomicAdd(&cnt[row], 1);
        if (pos < 16) cand[(row << 4) + pos] = i2[t][j]; else ovf = true;
      }
      if (ovf || m3[t][j] <= lim[t][j]) {
        int old = atomicOr(&flags[row], 1);
        if (old == 0) { int p = atomicAdd(nflag, 1); flist[p & (NROWS - 1)] = row; }
      }
    }
}

// Exact rescore: lane c replays the bit-exact np fp32 pipeline for candidate c;
// lexicographic (v, k) min == np.argmin first-occurrence. (r16/r18-proven)
__global__ __launch_bounds__(256) void rescore_kernel(
    const float* __restrict__ x, const float* __restrict__ W,
    const float* __restrict__ wsq, const float* __restrict__ xsq,
    const int* __restrict__ cnt, const int* __restrict__ cand,
    const int* __restrict__ flags,
    int* __restrict__ qout, float* __restrict__ out2) {
  const int wid = threadIdx.x >> 6, lane = threadIdx.x & 63;
  const int r = blockIdx.x * 4 + wid;
  if (flags[r]) return;   // exact path owns this row
  int c = cnt[r]; if (c > 16) c = 16;
  int best;
  if (c == 1) {
    best = cand[r << 4] & (K_ - 1);
  } else {
    const float* xr = x + ((size_t)(r >> 10) * D_) * T_ + (r & 1023);
    float v = INF_; int k = 0x7fffffff;
    if (lane < c) {
      k = cand[(r << 4) + lane] & (K_ - 1);
      const float* wr = W + (size_t)k * D_;
      float mm = 0.f;
#pragma unroll 16
      for (int d = 0; d < D_; ++d)
        mm = __fmaf_rn(xr[(size_t)d * T_], wr[d], mm);   // ascending-d sgemm chain
      v = __fadd_rn(__fmaf_rn(-2.f, mm, wsq[k]), xsq[r]);  // RN(wq-2mm) then +xsq
    }
#pragma unroll
    for (int mask = 1; mask < 16; mask <<= 1) {
      float vo = __shfl_xor(v, mask); int ko = __shfl_xor(k, mask);
      if (vo < v || (vo == v && ko < k)) { v = vo; k = ko; }
    }
    best = k & (K_ - 1);
  }
  if (lane == 0) { qout[r] = best; out2[r] = (float)best; }
}

// Exact full-scan v2 for flagged rows (expected ~0-1). Work item = (row,
// k-chunk of 1024): 4-way parallel per row; partial lex-min merged via u64
// atomicMin (deterministic: same values every replay). LDS-staged coalesced W.
__global__ __launch_bounds__(256) void exact_kernel(
    const float* __restrict__ x, const float* __restrict__ W,
    const float* __restrict__ wsq, const float* __restrict__ xsq,
    const int* __restrict__ nflag, const int* __restrict__ flist,
    unsigned long long* __restrict__ eslot) {
  __shared__ float xrow[128];
  __shared__ float wl[64][130];   // pad 130
  int n = *nflag; if (n > NROWS) n = NROWS;
  for (int item = blockIdx.x; item < n * 4; item += 256) {
    int r = flist[item >> 2] & (NROWS - 1);
    int chunk = item & 3;
    const float* xr = x + ((size_t)(r >> 10) * D_) * T_ + (r & 1023);
    __syncthreads();   // protect xrow/wl from previous item
    if (threadIdx.x < 128) xrow[threadIdx.x] = xr[(size_t)threadIdx.x * T_];
    float v = INF_; int kb = 0x7fffffff;
    for (int s = chunk * 16; s < chunk * 16 + 16; ++s) {
      __syncthreads();
      const f2* src = (const f2*)(W + (size_t)s * 64 * D_);
      for (int e = threadIdx.x; e < 4096; e += 256)
        *(f2*)&wl[e >> 6][(e & 63) * 2] = src[e];
      __syncthreads();
      if (threadIdx.x < 64) {
        int k = s * 64 + threadIdx.x;
        float mm = 0.f;
#pragma unroll 16
        for (int d = 0; d < D_; ++d)
          mm = __fmaf_rn(xrow[d], wl[threadIdx.x][d], mm);  // ascending-d chain
        float vv = __fadd_rn(__fmaf_rn(-2.f, mm, wsq[k]), xsq[r]);
        if (vv < v) { v = vv; kb = k; }   // strict < ; k ascending per lane
      }
    }
    if (threadIdx.x < 64) {
#pragma unroll
      for (int mask = 1; mask < 64; mask <<= 1) {
        float vo = __shfl_xor(v, mask); int ko = __shfl_xor(kb, mask);
        if (vo < v || (vo == v && ko < kb)) { v = vo; kb = ko; }
      }
      if (threadIdx.x == 0) {
        // v > 0 (distance ~128) => float bits are order-preserving
        unsigned long long pk =
            ((unsigned long long)__float_as_uint(v) << 32) | (unsigned)kb;
        atomicMin(&eslot[r], pk);
      }
    }
    __syncthreads();
  }
}

// Write flagged rows' winners from the u64 slots.
__global__ void finalize_kernel(const int* __restrict__ flags,
                                const unsigned long long* __restrict__ eslot,
                                int* __restrict__ qout, float* __restrict__ out2) {
  int r = blockIdx.x * 256 + threadIdx.x;
  if (flags[r]) {
    int best = (int)(unsigned)(eslot[r] & 0xFFFFFFFFull) & (K_ - 1);
    qout[r] = best; out2[r] = (float)best;
  }
}

// out0[r, d] = W[q[r], d]  — coalesced along d
__global__ void scatter0_kernel(const float* __restrict__ W,
                                const int* __restrict__ q,
                                float* __restrict__ out0) {
  int r = blockIdx.x * 2 + (threadIdx.x >> 7);
  int d = threadIdx.x & 127;
  int k = q[r] & (K_ - 1);
  out0[(size_t)r * D_ + d] = W[(size_t)k * D_ + d];
}

// out1[b, d, t] = W[q[b,t], d]  — coalesced along t
__global__ void scatter1_kernel(const float* __restrict__ W,
                                const int* __restrict__ q,
                                float* __restrict__ out1) {
  int b = blockIdx.x >> 7;
  int d = blockIdx.x & 127;
  for (int t = threadIdx.x; t < T_; t += 256) {
    int k = q[b * T_ + t] & (K_ - 1);
    out1[((size_t)b * D_ + d) * T_ + t] = W[(size_t)k * D_ + d];
  }
}

extern "C" void kernel_launch(void* const* d_in, const int* in_sizes, int n_in,
                              void* d_out, int out_size, void* d_ws, size_t ws_size,
                              hipStream_t stream) {
  const float* x = (const float*)d_in[0];
  const float* W = (const float*)d_in[1];
  float* out  = (float*)d_out;
  float* out0 = out;                           // [B,T,D]  4194304
  float* out1 = out + (size_t)NROWS * D_;      // [B,D,T]  4194304
  float* out2 = out + 2 * (size_t)NROWS * D_;  // [B,T]    32768 (as float)

  // small scratch in ws (532 KB, within the proven envelope)
  float*    wsq   = (float*)d_ws;                               // 16 KB
  float*    xsq   = (float*)((char*)d_ws + (16 << 10));         // 128 KB
  int*      q     = (int*)((char*)d_ws + (144 << 10));          // 128 KB
  int*      cnt   = (int*)((char*)d_ws + (272 << 10));          // 128 KB
  unsigned* maxw  = (unsigned*)((char*)d_ws + (400 << 10));     // 4 B (4K pad)
  int*      flags = (int*)((char*)d_ws + (404 << 10));          // 128 KB

  // big scratch in out0 (read before scatter0 overwrites it; stream-ordered)
  int*   cand  = (int*)out0;                                       // 2 MB
  short* WbfH  = (short*)((char*)(void*)out0 + (2 << 20));         // 1 MB
  short* WbfL  = (short*)((char*)(void*)out0 + (3 << 20));         // 1 MB
  int*   flist = (int*)((char*)(void*)out0 + (4 << 20));           // 128 KB
  int*   nflag = (int*)((char*)(void*)out0 + (4 << 20) + (128 << 10));  // 64 B
  unsigned long long* eslot =
      (unsigned long long*)((char*)(void*)out0 + (4 << 20) + (256 << 10));  // 256 KB

  // zero cnt + maxw + flags (272K..532K); zero nflag; eslot = all-ones (u64 max)
  hipMemsetAsync((char*)d_ws + (272 << 10), 0, (260 << 10) + 64, stream);
  hipMemsetAsync(nflag, 0, 64, stream);
  hipMemsetAsync(eslot, 0xFF, NROWS * sizeof(unsigned long long), stream);
  wsq_kernel<<<K_ / 256, 256, 0, stream>>>(W, wsq, maxw);
  wbf_prep_kernel<<<K_ * D_ / 256, 256, 0, stream>>>(W, WbfH, WbfL);
  filter_kernel<<<NROWS / 32, 256, 0, stream>>>(x, WbfH, WbfL, wsq, maxw, xsq,
                                                cnt, cand, flags, nflag, flist);
  rescore_kernel<<<NROWS / 4, 256, 0, stream>>>(x, W, wsq, xsq, cnt, cand, flags, q, out2);
  exact_kernel<<<256, 256, 0, stream>>>(x, W, wsq, xsq, nflag, flist, eslot);
  finalize_kernel<<<NROWS / 256, 256, 0, stream>>>(flags, eslot, q, out2);
  scatter0_kernel<<<NROWS / 2, 256, 0, stream>>>(W, q, out0);
  scatter1_kernel<<<B_ * D_, 256, 0, stream>>>(W, q, out1);
}